// Round 5
// baseline (464.535 us; speedup 1.0000x reference)
//
#include <hip/hip_runtime.h>
#include <hip/hip_bf16.h>
#include <math.h>

// ---------------------------------------------------------------------------
// GCN: 3x GCNConv(128->128) + fused (Wp1@Wp2) head + log_softmax.
// Round 5: column-split aggregation (2 passes, 12.8 MB working set each ->
// higher L2 hit rate; gather path showed a flat ~3.6 TB/s L2-miss ceiling),
// cast_x fused into layer-1 MFMA GEMM, weight-prep kernels merged.
// ---------------------------------------------------------------------------

#define DH 128    // feature dim (D == H == 128)
#define NC 40     // classes
#define BN 256    // nodes per bucket
#define MAXNB 512 // max buckets (N <= 131072)
#define CH 8192   // edges per scatter block
#define ECAP 6144 // LDS edge capacity in bucket_csr

typedef __attribute__((ext_vector_type(8))) short bf16x8;
typedef __attribute__((ext_vector_type(4))) float f32x4;

__device__ __forceinline__ unsigned short f2bf(float f) {
    unsigned u = __float_as_uint(f);
    unsigned r = (u + 0x7fffu + ((u >> 16) & 1u)) >> 16;   // RNE
    return (unsigned short)r;
}
__device__ __forceinline__ unsigned pack2(float lo, float hi) {
    return (unsigned)f2bf(lo) | ((unsigned)f2bf(hi) << 16);
}

// ---------------- bucket-level histogram (LDS, then coalesced merge) --------

__global__ __launch_bounds__(256) void bucket_hist(const int* __restrict__ dst, int E,
                                                   unsigned* __restrict__ bcnt) {
    __shared__ unsigned h[MAXNB];
    int tid = threadIdx.x;
    for (int i = tid; i < MAXNB; i += 256) h[i] = 0;
    __syncthreads();
    int e0 = blockIdx.x * CH;
    int e1 = min(e0 + CH, E);
    for (int i = e0 + tid; i < e1; i += 256)
        atomicAdd(&h[dst[i] >> 8], 1u);
    __syncthreads();
    for (int i = tid; i < MAXNB; i += 256)
        if (h[i]) atomicAdd(&bcnt[i], h[i]);
}

__global__ __launch_bounds__(256) void bucket_alloc(const unsigned* __restrict__ bcnt,
                                                    unsigned* __restrict__ bbase,
                                                    unsigned* __restrict__ bpos,
                                                    unsigned* __restrict__ cursor, int NB) {
    int i = blockIdx.x * 256 + threadIdx.x;
    if (i < NB) {
        unsigned c = bcnt[i];
        unsigned o = atomicAdd(cursor, c);
        bbase[i] = o;
        bpos[i] = o;
    }
}

__global__ __launch_bounds__(256) void bucket_scatter(const int* __restrict__ src,
                                                      const int* __restrict__ dst, int E,
                                                      unsigned* __restrict__ bpos,
                                                      unsigned* __restrict__ ebuf) {
    __shared__ unsigned hist[MAXNB];
    __shared__ unsigned lbase[MAXNB];
    __shared__ unsigned gbase[MAXNB];
    __shared__ unsigned cur[MAXNB];
    __shared__ unsigned sorted[CH];
    __shared__ unsigned short sbkt[CH];
    __shared__ unsigned total;

    int tid = threadIdx.x;
    int e0 = blockIdx.x * CH;
    int nE = min(CH, E - e0);

    for (int i = tid; i < MAXNB; i += 256) { hist[i] = 0; cur[i] = 0; }
    if (tid == 0) total = 0;
    __syncthreads();

    for (int i = tid; i < nE; i += 256)
        atomicAdd(&hist[dst[e0 + i] >> 8], 1u);
    __syncthreads();

    for (int i = tid; i < MAXNB; i += 256) {
        unsigned h = hist[i];
        lbase[i] = h ? atomicAdd(&total, h) : 0u;
        gbase[i] = h ? atomicAdd(&bpos[i], h) : 0u;
    }
    __syncthreads();

    for (int i = tid; i < nE; i += 256) {
        int s = src[e0 + i];
        int d = dst[e0 + i];
        unsigned b = (unsigned)d >> 8;
        unsigned r = atomicAdd(&cur[b], 1u);
        unsigned p = lbase[b] + r;
        sorted[p] = ((unsigned)s << 8) | ((unsigned)d & 255u);
        sbkt[p] = (unsigned short)b;
    }
    __syncthreads();

    for (int p = tid; p < nE; p += 256) {
        unsigned b = sbkt[p];
        ebuf[gbase[b] + (p - lbase[b])] = sorted[p];
    }
}

__global__ __launch_bounds__(256) void bucket_csr(const unsigned* __restrict__ ebuf,
                                                  const unsigned* __restrict__ bbase,
                                                  const unsigned* __restrict__ bcnt,
                                                  unsigned* __restrict__ off,
                                                  unsigned* __restrict__ cnt,
                                                  float* __restrict__ nrm,
                                                  int* __restrict__ csr, int N) {
    __shared__ unsigned h[BN];
    __shared__ unsigned nb[BN];
    __shared__ unsigned ncur[BN];
    __shared__ int lcsr[ECAP];
    __shared__ unsigned tot;

    int b = blockIdx.x;
    int tid = threadIdx.x;
    unsigned ebase = bbase[b];
    unsigned ecnt = bcnt[b];

    h[tid] = 0;
    if (tid == 0) tot = 0;
    __syncthreads();

    for (unsigned i = tid; i < ecnt; i += 256)
        atomicAdd(&h[ebuf[ebase + i] & 255u], 1u);
    __syncthreads();

    unsigned myh = h[tid];
    unsigned mybase = myh ? atomicAdd(&tot, myh) : 0u;
    nb[tid] = mybase;
    ncur[tid] = 0;
    int node = b * BN + tid;
    if (node < N) {
        off[node] = ebase + mybase;
        cnt[node] = myh;
        nrm[node] = rsqrtf((float)myh + 1.0f);
    }
    __syncthreads();

    if (ecnt <= ECAP) {
        for (unsigned i = tid; i < ecnt; i += 256) {
            unsigned v = ebuf[ebase + i];
            unsigned nl = v & 255u;
            unsigned r = atomicAdd(&ncur[nl], 1u);
            lcsr[nb[nl] + r] = (int)(v >> 8);
        }
        __syncthreads();
        for (unsigned i = tid; i < ecnt; i += 256)
            csr[ebase + i] = lcsr[i];
    } else {
        for (unsigned i = tid; i < ecnt; i += 256) {
            unsigned v = ebuf[ebase + i];
            unsigned nl = v & 255u;
            unsigned r = atomicAdd(&ncur[nl], 1u);
            csr[ebase + nb[nl] + r] = (int)(v >> 8);
        }
    }
}

// ---------------- weight prep: Wt (3 layers, transposed bf16) + fused head --

__global__ __launch_bounds__(256) void prep_w(const float* __restrict__ W1,
                                              const float* __restrict__ W2,
                                              const float* __restrict__ W3,
                                              const float* __restrict__ Wp1,
                                              const float* __restrict__ bp1,
                                              const float* __restrict__ Wp2,
                                              const float* __restrict__ bp2,
                                              unsigned short* __restrict__ Wt,
                                              unsigned short* __restrict__ Wft,
                                              float* __restrict__ bfh) {
    int id = blockIdx.x * 256 + threadIdx.x;
    if (id < 3 * DH * DH) {
        int l = id >> 14, r = id & (DH * DH - 1);
        int k = r >> 7, n = r & 127;
        const float* W = (l == 0) ? W1 : (l == 1) ? W2 : W3;
        Wt[l * DH * DH + n * DH + k] = f2bf(W[k * DH + n]);
    } else if (id < 3 * DH * DH + 48 * DH) {
        int o = id - 3 * DH * DH;
        int c = o >> 7, k = o & 127;
        float acc = 0.f;
        if (c < NC)
            for (int j = 0; j < DH; ++j) acc += Wp1[k * DH + j] * Wp2[j * NC + c];
        Wft[c * DH + k] = f2bf(acc);
    } else if (id < 3 * DH * DH + 48 * DH + 48) {
        int c = id - 3 * DH * DH - 48 * DH;
        float acc = 0.f;
        if (c < NC) {
            acc = bp2[c];
            for (int j = 0; j < DH; ++j) acc += bp1[j] * Wp2[j * NC + c];
        }
        bfh[c] = acc;
    }
}

// ---------------- MFMA GEMM: out_bf16[r][:] = bf16(nrm[r] * (X @ W)) --------
// 16x16x32 bf16 MFMA. A[m=lane&15][k=quad*8+j]; B from Wt[n][k] (contig);
// C/D: col=lane&15, row=quad*4+reg. Block=128 rows, wave=32 rows x 128 cols.

__global__ __launch_bounds__(256) void gemm_mfma(const unsigned short* __restrict__ Xb,
                                                 const unsigned short* __restrict__ Wt,
                                                 const float* __restrict__ nrm,
                                                 unsigned short* __restrict__ outb,
                                                 int nrows) {
    const int tid = threadIdx.x;
    const int wave = tid >> 6;
    const int lane = tid & 63;
    const int m = lane & 15;
    const int quad = lane >> 4;
    const int rbase = blockIdx.x * 128 + wave * 32;

    f32x4 acc[2][8];
#pragma unroll
    for (int rt = 0; rt < 2; ++rt)
#pragma unroll
        for (int ct = 0; ct < 8; ++ct) acc[rt][ct] = (f32x4){0.f, 0.f, 0.f, 0.f};

#pragma unroll
    for (int kt = 0; kt < 4; ++kt) {
        const int kof = kt * 32 + quad * 8;
        bf16x8 a[2], b[8];
#pragma unroll
        for (int rt = 0; rt < 2; ++rt) {
            int r = rbase + rt * 16 + m;
            r = (r < nrows) ? r : (nrows - 1);
            a[rt] = *(const bf16x8*)(Xb + (size_t)r * DH + kof);
        }
#pragma unroll
        for (int ct = 0; ct < 8; ++ct)
            b[ct] = *(const bf16x8*)(Wt + (ct * 16 + m) * DH + kof);
#pragma unroll
        for (int rt = 0; rt < 2; ++rt)
#pragma unroll
            for (int ct = 0; ct < 8; ++ct)
                acc[rt][ct] = __builtin_amdgcn_mfma_f32_16x16x32_bf16(a[rt], b[ct], acc[rt][ct], 0, 0, 0);
    }

#pragma unroll
    for (int rt = 0; rt < 2; ++rt)
#pragma unroll
        for (int reg = 0; reg < 4; ++reg) {
            int r = rbase + rt * 16 + quad * 4 + reg;
            if (r < nrows) {
                float s = nrm[r];
#pragma unroll
                for (int ct = 0; ct < 8; ++ct)
                    outb[(size_t)r * DH + ct * 16 + m] = f2bf(acc[rt][ct][reg] * s);
            }
        }
}

// layer-1 variant: reads fp32 X, packs bf16 A-frags inline (bit-identical to
// cast_x + gemm_mfma, kills one full N*DH round trip + a launch).

__global__ __launch_bounds__(256) void gemm_mfma_f32(const float* __restrict__ X,
                                                     const unsigned short* __restrict__ Wt,
                                                     const float* __restrict__ nrm,
                                                     unsigned short* __restrict__ outb,
                                                     int nrows) {
    const int tid = threadIdx.x;
    const int wave = tid >> 6;
    const int lane = tid & 63;
    const int m = lane & 15;
    const int quad = lane >> 4;
    const int rbase = blockIdx.x * 128 + wave * 32;

    union U8 { bf16x8 v; unsigned u[4]; };

    f32x4 acc[2][8];
#pragma unroll
    for (int rt = 0; rt < 2; ++rt)
#pragma unroll
        for (int ct = 0; ct < 8; ++ct) acc[rt][ct] = (f32x4){0.f, 0.f, 0.f, 0.f};

#pragma unroll
    for (int kt = 0; kt < 4; ++kt) {
        const int kof = kt * 32 + quad * 8;
        bf16x8 a[2], b[8];
#pragma unroll
        for (int rt = 0; rt < 2; ++rt) {
            int r = rbase + rt * 16 + m;
            r = (r < nrows) ? r : (nrows - 1);
            const float* p = X + (size_t)r * DH + kof;
            float4 u0 = *(const float4*)p;
            float4 u1 = *(const float4*)(p + 4);
            U8 t;
            t.u[0] = pack2(u0.x, u0.y);
            t.u[1] = pack2(u0.z, u0.w);
            t.u[2] = pack2(u1.x, u1.y);
            t.u[3] = pack2(u1.z, u1.w);
            a[rt] = t.v;
        }
#pragma unroll
        for (int ct = 0; ct < 8; ++ct)
            b[ct] = *(const bf16x8*)(Wt + (ct * 16 + m) * DH + kof);
#pragma unroll
        for (int rt = 0; rt < 2; ++rt)
#pragma unroll
            for (int ct = 0; ct < 8; ++ct)
                acc[rt][ct] = __builtin_amdgcn_mfma_f32_16x16x32_bf16(a[rt], b[ct], acc[rt][ct], 0, 0, 0);
    }

#pragma unroll
    for (int rt = 0; rt < 2; ++rt)
#pragma unroll
        for (int reg = 0; reg < 4; ++reg) {
            int r = rbase + rt * 16 + quad * 4 + reg;
            if (r < nrows) {
                float s = nrm[r];
#pragma unroll
                for (int ct = 0; ct < 8; ++ct)
                    outb[(size_t)r * DH + ct * 16 + m] = f2bf(acc[rt][ct][reg] * s);
            }
        }
}

// ---------------- CSR aggregation, column-split -----------------------------
// gridDim.y = 2 halves; each pass touches a 12.8 MB slice of Abf (vs 4 MB
// per-XCD L2) to raise L2 hit rate on the random gather. 16 lanes/node,
// uint2 (4 bf16 cols) per lane, 8-deep edge unroll (64 B in flight / group).

__device__ __forceinline__ void bf4_add(float* acc, uint2 v) {
    acc[0] += __uint_as_float(v.x << 16);
    acc[1] += __uint_as_float(v.x & 0xffff0000u);
    acc[2] += __uint_as_float(v.y << 16);
    acc[3] += __uint_as_float(v.y & 0xffff0000u);
}

__global__ __launch_bounds__(256) void aggregate(const uint2* __restrict__ Abf,
                                                 const int* __restrict__ csr,
                                                 const unsigned* __restrict__ off,
                                                 const unsigned* __restrict__ cnt,
                                                 const float* __restrict__ nrm,
                                                 const float* __restrict__ bias,
                                                 unsigned short* __restrict__ Bb, int N) {
    int node = blockIdx.x * 16 + (threadIdx.x >> 4);
    int lane = threadIdx.x & 15;
    int half = blockIdx.y;
    if (node >= N) return;

    const int cidx = half * 16 + lane;      // uint2 index within row (0..31)

    float acc[4];
    {
        uint2 v = Abf[(size_t)node * 32 + cidx];   // self term
        acc[0] = __uint_as_float(v.x << 16);
        acc[1] = __uint_as_float(v.x & 0xffff0000u);
        acc[2] = __uint_as_float(v.y << 16);
        acc[3] = __uint_as_float(v.y & 0xffff0000u);
    }
    unsigned o = off[node];
    unsigned d = cnt[node];

    unsigned e = 0;
    for (; e + 8 <= d; e += 8) {
        int s0 = csr[o + e + 0];
        int s1 = csr[o + e + 1];
        int s2 = csr[o + e + 2];
        int s3 = csr[o + e + 3];
        int s4 = csr[o + e + 4];
        int s5 = csr[o + e + 5];
        int s6 = csr[o + e + 6];
        int s7 = csr[o + e + 7];
        uint2 v0 = Abf[(size_t)s0 * 32 + cidx];
        uint2 v1 = Abf[(size_t)s1 * 32 + cidx];
        uint2 v2 = Abf[(size_t)s2 * 32 + cidx];
        uint2 v3 = Abf[(size_t)s3 * 32 + cidx];
        uint2 v4 = Abf[(size_t)s4 * 32 + cidx];
        uint2 v5 = Abf[(size_t)s5 * 32 + cidx];
        uint2 v6 = Abf[(size_t)s6 * 32 + cidx];
        uint2 v7 = Abf[(size_t)s7 * 32 + cidx];
        bf4_add(acc, v0); bf4_add(acc, v1); bf4_add(acc, v2); bf4_add(acc, v3);
        bf4_add(acc, v4); bf4_add(acc, v5); bf4_add(acc, v6); bf4_add(acc, v7);
    }
    for (; e < d; ++e) {
        int s = csr[o + e];
        uint2 v = Abf[(size_t)s * 32 + cidx];
        bf4_add(acc, v);
    }

    float nm = nrm[node];
    float4 b4 = *(const float4*)(bias + cidx * 4);
    float r0 = fmaxf(acc[0] * nm + b4.x, 0.f);
    float r1 = fmaxf(acc[1] * nm + b4.y, 0.f);
    float r2 = fmaxf(acc[2] * nm + b4.z, 0.f);
    float r3 = fmaxf(acc[3] * nm + b4.w, 0.f);
    uint2 ov;
    ov.x = pack2(r0, r1);
    ov.y = pack2(r2, r3);
    ((uint2*)Bb)[(size_t)node * 32 + cidx] = ov;
}

// ---------------- MFMA head + log_softmax -----------------------------------

__global__ __launch_bounds__(256) void final_mfma(const unsigned short* __restrict__ Xb,
                                                  const unsigned short* __restrict__ Wft,
                                                  const float* __restrict__ bfh,
                                                  float* __restrict__ out, int nrows) {
    const int tid = threadIdx.x;
    const int wave = tid >> 6;
    const int lane = tid & 63;
    const int m = lane & 15;
    const int quad = lane >> 4;
    const int rbase = blockIdx.x * 64 + wave * 16;

    f32x4 acc[3];
#pragma unroll
    for (int ct = 0; ct < 3; ++ct) acc[ct] = (f32x4){0.f, 0.f, 0.f, 0.f};

#pragma unroll
    for (int kt = 0; kt < 4; ++kt) {
        const int kof = kt * 32 + quad * 8;
        int r = rbase + m;
        r = (r < nrows) ? r : (nrows - 1);
        bf16x8 a = *(const bf16x8*)(Xb + (size_t)r * DH + kof);
#pragma unroll
        for (int ct = 0; ct < 3; ++ct) {
            bf16x8 b = *(const bf16x8*)(Wft + (ct * 16 + m) * DH + kof);
            acc[ct] = __builtin_amdgcn_mfma_f32_16x16x32_bf16(a, b, acc[ct], 0, 0, 0);
        }
    }

    float bias0 = bfh[m];
    float bias1 = bfh[16 + m];
    float bias2 = bfh[32 + m];

#pragma unroll
    for (int reg = 0; reg < 4; ++reg) {
        float v0 = acc[0][reg] + bias0;
        float v1 = acc[1][reg] + bias1;
        float v2 = (m < 8) ? (acc[2][reg] + bias2) : -1e30f;
        float mx = fmaxf(fmaxf(v0, v1), v2);
#pragma unroll
        for (int dlt = 1; dlt < 16; dlt <<= 1) mx = fmaxf(mx, __shfl_xor(mx, dlt));
        float s = __expf(v0 - mx) + __expf(v1 - mx) + ((m < 8) ? __expf(v2 - mx) : 0.f);
#pragma unroll
        for (int dlt = 1; dlt < 16; dlt <<= 1) s += __shfl_xor(s, dlt);
        float ls = mx + __logf(s);
        int r = rbase + quad * 4 + reg;
        if (r < nrows) {
            out[(size_t)r * NC + m] = v0 - ls;
            out[(size_t)r * NC + 16 + m] = v1 - ls;
            if (m < 8) out[(size_t)r * NC + 32 + m] = v2 - ls;
        }
    }
}

// ---------------------------------------------------------------------------

extern "C" void kernel_launch(void* const* d_in, const int* in_sizes, int n_in,
                              void* d_out, int out_size, void* d_ws, size_t ws_size,
                              hipStream_t stream) {
    const float* x   = (const float*)d_in[0];
    const int*   ei  = (const int*)d_in[1];
    const float* W1  = (const float*)d_in[2];
    const float* b1  = (const float*)d_in[3];
    const float* W2  = (const float*)d_in[4];
    const float* b2  = (const float*)d_in[5];
    const float* W3  = (const float*)d_in[6];
    const float* b3  = (const float*)d_in[7];
    const float* Wp1 = (const float*)d_in[8];
    const float* bp1 = (const float*)d_in[9];
    const float* Wp2 = (const float*)d_in[10];
    const float* bp2 = (const float*)d_in[11];
    float* out = (float*)d_out;

    const int N = in_sizes[0] / DH;
    const int E = in_sizes[1] / 2;
    const int* src = ei;
    const int* dst = ei + E;
    const int NB = (N + BN - 1) / BN;

    // workspace carve (all 16B aligned)
    char* w = (char*)d_ws;
    unsigned short* Ab  = (unsigned short*)w; w += (size_t)N * DH * 2;
    unsigned short* Bb  = (unsigned short*)w; w += (size_t)N * DH * 2;
    int*      csr    = (int*)w;      w += (size_t)E * 4;
    unsigned* ebuf   = (unsigned*)w; w += (size_t)E * 4;
    unsigned* bcnt   = (unsigned*)w; w += MAXNB * 4;
    unsigned* cursor = (unsigned*)w; w += 16;
    unsigned* bbase  = (unsigned*)w; w += MAXNB * 4;
    unsigned* bpos   = (unsigned*)w; w += MAXNB * 4;
    unsigned* off    = (unsigned*)w; w += (size_t)N * 4;
    unsigned* cnt    = (unsigned*)w; w += (size_t)N * 4;
    float*    nrm    = (float*)w;    w += (size_t)N * 4;
    unsigned short* Wt  = (unsigned short*)w; w += 3 * DH * DH * 2;
    unsigned short* Wft = (unsigned short*)w; w += 48 * DH * 2;
    float*    bfh    = (float*)w;    w += 64 * 4;

    const int gC = (E + CH - 1) / CH;

    hipMemsetAsync(bcnt, 0, MAXNB * 4 + 16, stream);   // bcnt + cursor
    bucket_hist   <<<gC, 256, 0, stream>>>(dst, E, bcnt);
    bucket_alloc  <<<(NB + 255) / 256, 256, 0, stream>>>(bcnt, bbase, bpos, cursor, NB);
    bucket_scatter<<<gC, 256, 0, stream>>>(src, dst, E, bpos, ebuf);
    bucket_csr    <<<NB, 256, 0, stream>>>(ebuf, bbase, bcnt, off, cnt, nrm, csr, N);
    prep_w<<<(3 * DH * DH + 48 * DH + 48 + 255) / 256, 256, 0, stream>>>(
        W1, W2, W3, Wp1, bp1, Wp2, bp2, Wt, Wft, bfh);

    const int gG = (N + 127) / 128;
    const dim3 gA((N + 15) / 16, 2);

    gemm_mfma_f32<<<gG, 256, 0, stream>>>(x, Wt, nrm, Ab, N);
    aggregate<<<gA, 256, 0, stream>>>((const uint2*)Ab, csr, off, cnt, nrm, b1, Bb, N);
    gemm_mfma<<<gG, 256, 0, stream>>>(Bb, Wt + DH * DH,     nrm, Ab, N);
    aggregate<<<gA, 256, 0, stream>>>((const uint2*)Ab, csr, off, cnt, nrm, b2, Bb, N);
    gemm_mfma<<<gG, 256, 0, stream>>>(Bb, Wt + 2 * DH * DH, nrm, Ab, N);
    aggregate<<<gA, 256, 0, stream>>>((const uint2*)Ab, csr, off, cnt, nrm, b3, Bb, N);

    final_mfma<<<(N + 63) / 64, 256, 0, stream>>>(Bb, Wft, bfh, out, N);
}

// Round 6
// 418.020 us; speedup vs baseline: 1.1113x; 1.1113x over previous
//
#include <hip/hip_runtime.h>
#include <hip/hip_bf16.h>
#include <math.h>

// ---------------------------------------------------------------------------
// GCN: 3x GCNConv(128->128) + fused (Wp1@Wp2) head + log_softmax.
// Round 6: revert round-5 column split (gather is at its structural floor:
// ~8 XCD x 25.6 MB replicated misses at the ~3.7 TB/s random-access fabric
// ceiling). Fuse GEMM into aggregate epilogue (LDS bf16 tile + MFMA) and the
// head+log_softmax into layer-3's aggregate: kills the Bb round-trip
// (51 MB/layer) and 4 launches. All cast points identical -> bit-identical.
// ---------------------------------------------------------------------------

#define DH 128    // feature dim (D == H == 128)
#define NC 40     // classes
#define BN 256    // nodes per bucket
#define MAXNB 512 // max buckets (N <= 131072)
#define CH 8192   // edges per scatter block
#define ECAP 6144 // LDS edge capacity in bucket_csr
#define SP 136    // LDS row stride (elems): 128 + 8 pad -> breaks 256B-stride bank conflict

typedef __attribute__((ext_vector_type(8))) short bf16x8;
typedef __attribute__((ext_vector_type(4))) float f32x4;

__device__ __forceinline__ unsigned short f2bf(float f) {
    unsigned u = __float_as_uint(f);
    unsigned r = (u + 0x7fffu + ((u >> 16) & 1u)) >> 16;   // RNE
    return (unsigned short)r;
}
__device__ __forceinline__ unsigned pack2(float lo, float hi) {
    return (unsigned)f2bf(lo) | ((unsigned)f2bf(hi) << 16);
}

// ---------------- bucket-level histogram (LDS, then coalesced merge) --------

__global__ __launch_bounds__(256) void bucket_hist(const int* __restrict__ dst, int E,
                                                   unsigned* __restrict__ bcnt) {
    __shared__ unsigned h[MAXNB];
    int tid = threadIdx.x;
    for (int i = tid; i < MAXNB; i += 256) h[i] = 0;
    __syncthreads();
    int e0 = blockIdx.x * CH;
    int e1 = min(e0 + CH, E);
    for (int i = e0 + tid; i < e1; i += 256)
        atomicAdd(&h[dst[i] >> 8], 1u);
    __syncthreads();
    for (int i = tid; i < MAXNB; i += 256)
        if (h[i]) atomicAdd(&bcnt[i], h[i]);
}

__global__ __launch_bounds__(256) void bucket_alloc(const unsigned* __restrict__ bcnt,
                                                    unsigned* __restrict__ bbase,
                                                    unsigned* __restrict__ bpos,
                                                    unsigned* __restrict__ cursor, int NB) {
    int i = blockIdx.x * 256 + threadIdx.x;
    if (i < NB) {
        unsigned c = bcnt[i];
        unsigned o = atomicAdd(cursor, c);
        bbase[i] = o;
        bpos[i] = o;
    }
}

__global__ __launch_bounds__(256) void bucket_scatter(const int* __restrict__ src,
                                                      const int* __restrict__ dst, int E,
                                                      unsigned* __restrict__ bpos,
                                                      unsigned* __restrict__ ebuf) {
    __shared__ unsigned hist[MAXNB];
    __shared__ unsigned lbase[MAXNB];
    __shared__ unsigned gbase[MAXNB];
    __shared__ unsigned cur[MAXNB];
    __shared__ unsigned sorted[CH];
    __shared__ unsigned short sbkt[CH];
    __shared__ unsigned total;

    int tid = threadIdx.x;
    int e0 = blockIdx.x * CH;
    int nE = min(CH, E - e0);

    for (int i = tid; i < MAXNB; i += 256) { hist[i] = 0; cur[i] = 0; }
    if (tid == 0) total = 0;
    __syncthreads();

    for (int i = tid; i < nE; i += 256)
        atomicAdd(&hist[dst[e0 + i] >> 8], 1u);
    __syncthreads();

    for (int i = tid; i < MAXNB; i += 256) {
        unsigned h = hist[i];
        lbase[i] = h ? atomicAdd(&total, h) : 0u;
        gbase[i] = h ? atomicAdd(&bpos[i], h) : 0u;
    }
    __syncthreads();

    for (int i = tid; i < nE; i += 256) {
        int s = src[e0 + i];
        int d = dst[e0 + i];
        unsigned b = (unsigned)d >> 8;
        unsigned r = atomicAdd(&cur[b], 1u);
        unsigned p = lbase[b] + r;
        sorted[p] = ((unsigned)s << 8) | ((unsigned)d & 255u);
        sbkt[p] = (unsigned short)b;
    }
    __syncthreads();

    for (int p = tid; p < nE; p += 256) {
        unsigned b = sbkt[p];
        ebuf[gbase[b] + (p - lbase[b])] = sorted[p];
    }
}

__global__ __launch_bounds__(256) void bucket_csr(const unsigned* __restrict__ ebuf,
                                                  const unsigned* __restrict__ bbase,
                                                  const unsigned* __restrict__ bcnt,
                                                  unsigned* __restrict__ off,
                                                  unsigned* __restrict__ cnt,
                                                  float* __restrict__ nrm,
                                                  int* __restrict__ csr, int N) {
    __shared__ unsigned h[BN];
    __shared__ unsigned nb[BN];
    __shared__ unsigned ncur[BN];
    __shared__ int lcsr[ECAP];
    __shared__ unsigned tot;

    int b = blockIdx.x;
    int tid = threadIdx.x;
    unsigned ebase = bbase[b];
    unsigned ecnt = bcnt[b];

    h[tid] = 0;
    if (tid == 0) tot = 0;
    __syncthreads();

    for (unsigned i = tid; i < ecnt; i += 256)
        atomicAdd(&h[ebuf[ebase + i] & 255u], 1u);
    __syncthreads();

    unsigned myh = h[tid];
    unsigned mybase = myh ? atomicAdd(&tot, myh) : 0u;
    nb[tid] = mybase;
    ncur[tid] = 0;
    int node = b * BN + tid;
    if (node < N) {
        off[node] = ebase + mybase;
        cnt[node] = myh;
        nrm[node] = rsqrtf((float)myh + 1.0f);
    }
    __syncthreads();

    if (ecnt <= ECAP) {
        for (unsigned i = tid; i < ecnt; i += 256) {
            unsigned v = ebuf[ebase + i];
            unsigned nl = v & 255u;
            unsigned r = atomicAdd(&ncur[nl], 1u);
            lcsr[nb[nl] + r] = (int)(v >> 8);
        }
        __syncthreads();
        for (unsigned i = tid; i < ecnt; i += 256)
            csr[ebase + i] = lcsr[i];
    } else {
        for (unsigned i = tid; i < ecnt; i += 256) {
            unsigned v = ebuf[ebase + i];
            unsigned nl = v & 255u;
            unsigned r = atomicAdd(&ncur[nl], 1u);
            csr[ebase + nb[nl] + r] = (int)(v >> 8);
        }
    }
}

// ---------------- weight prep: Wt (3 layers, transposed bf16) + fused head --

__global__ __launch_bounds__(256) void prep_w(const float* __restrict__ W1,
                                              const float* __restrict__ W2,
                                              const float* __restrict__ W3,
                                              const float* __restrict__ Wp1,
                                              const float* __restrict__ bp1,
                                              const float* __restrict__ Wp2,
                                              const float* __restrict__ bp2,
                                              unsigned short* __restrict__ Wt,
                                              unsigned short* __restrict__ Wft,
                                              float* __restrict__ bfh) {
    int id = blockIdx.x * 256 + threadIdx.x;
    if (id < 3 * DH * DH) {
        int l = id >> 14, r = id & (DH * DH - 1);
        int k = r >> 7, n = r & 127;
        const float* W = (l == 0) ? W1 : (l == 1) ? W2 : W3;
        Wt[l * DH * DH + n * DH + k] = f2bf(W[k * DH + n]);
    } else if (id < 3 * DH * DH + 48 * DH) {
        int o = id - 3 * DH * DH;
        int c = o >> 7, k = o & 127;
        float acc = 0.f;
        if (c < NC)
            for (int j = 0; j < DH; ++j) acc += Wp1[k * DH + j] * Wp2[j * NC + c];
        Wft[c * DH + k] = f2bf(acc);
    } else if (id < 3 * DH * DH + 48 * DH + 48) {
        int c = id - 3 * DH * DH - 48 * DH;
        float acc = 0.f;
        if (c < NC) {
            acc = bp2[c];
            for (int j = 0; j < DH; ++j) acc += bp1[j] * Wp2[j * NC + c];
        }
        bfh[c] = acc;
    }
}

// ---------------- layer-1 MFMA GEMM: Ab = bf16(nrm * (x_f32 @ W1)) ----------
// 16x16x32 bf16 MFMA. A[m=lane&15][k=quad*8+j]; B from Wt[n][k] (contig);
// C/D: col=lane&15, row=quad*4+reg. Block=128 rows, wave=32 rows x 128 cols.

__global__ __launch_bounds__(256) void gemm_mfma_f32(const float* __restrict__ X,
                                                     const unsigned short* __restrict__ Wt,
                                                     const float* __restrict__ nrm,
                                                     unsigned short* __restrict__ outb,
                                                     int nrows) {
    const int tid = threadIdx.x;
    const int wave = tid >> 6;
    const int lane = tid & 63;
    const int m = lane & 15;
    const int quad = lane >> 4;
    const int rbase = blockIdx.x * 128 + wave * 32;

    union U8 { bf16x8 v; unsigned u[4]; };

    f32x4 acc[2][8];
#pragma unroll
    for (int rt = 0; rt < 2; ++rt)
#pragma unroll
        for (int ct = 0; ct < 8; ++ct) acc[rt][ct] = (f32x4){0.f, 0.f, 0.f, 0.f};

#pragma unroll
    for (int kt = 0; kt < 4; ++kt) {
        const int kof = kt * 32 + quad * 8;
        bf16x8 a[2], b[8];
#pragma unroll
        for (int rt = 0; rt < 2; ++rt) {
            int r = rbase + rt * 16 + m;
            r = (r < nrows) ? r : (nrows - 1);
            const float* p = X + (size_t)r * DH + kof;
            float4 u0 = *(const float4*)p;
            float4 u1 = *(const float4*)(p + 4);
            U8 t;
            t.u[0] = pack2(u0.x, u0.y);
            t.u[1] = pack2(u0.z, u0.w);
            t.u[2] = pack2(u1.x, u1.y);
            t.u[3] = pack2(u1.z, u1.w);
            a[rt] = t.v;
        }
#pragma unroll
        for (int ct = 0; ct < 8; ++ct)
            b[ct] = *(const bf16x8*)(Wt + (ct * 16 + m) * DH + kof);
#pragma unroll
        for (int rt = 0; rt < 2; ++rt)
#pragma unroll
            for (int ct = 0; ct < 8; ++ct)
                acc[rt][ct] = __builtin_amdgcn_mfma_f32_16x16x32_bf16(a[rt], b[ct], acc[rt][ct], 0, 0, 0);
    }

#pragma unroll
    for (int rt = 0; rt < 2; ++rt)
#pragma unroll
        for (int reg = 0; reg < 4; ++reg) {
            int r = rbase + rt * 16 + quad * 4 + reg;
            if (r < nrows) {
                float s = nrm[r];
#pragma unroll
                for (int ct = 0; ct < 8; ++ct)
                    outb[(size_t)r * DH + ct * 16 + m] = f2bf(acc[rt][ct][reg] * s);
            }
        }
}

// ---------------- gather phase (shared by fused kernels) --------------------
// 16 lanes/node, uint4 (8 bf16) per lane, 4-deep unroll. Result: the layer
// output z = relu(nrm*(sum+self)+bias) cast bf16 into sA[16][SP].

__device__ __forceinline__ void bf8_add(float* acc, uint4 v) {
    acc[0] += __uint_as_float(v.x << 16);
    acc[1] += __uint_as_float(v.x & 0xffff0000u);
    acc[2] += __uint_as_float(v.y << 16);
    acc[3] += __uint_as_float(v.y & 0xffff0000u);
    acc[4] += __uint_as_float(v.z << 16);
    acc[5] += __uint_as_float(v.z & 0xffff0000u);
    acc[6] += __uint_as_float(v.w << 16);
    acc[7] += __uint_as_float(v.w & 0xffff0000u);
}

__device__ __forceinline__ void gather_phase(const uint4* __restrict__ Abf,
                                             const int* __restrict__ csr,
                                             const unsigned* __restrict__ off,
                                             const unsigned* __restrict__ cnt,
                                             const float* __restrict__ nrm,
                                             const float* __restrict__ bias,
                                             unsigned short (*sA)[SP], int N) {
    const int tid = threadIdx.x;
    const int g = tid >> 4;
    const int lane = tid & 15;
    const int node = blockIdx.x * 16 + g;
    if (node < N) {
        float acc[8];
        {
            uint4 v = Abf[(size_t)node * 16 + lane];   // self term
            acc[0] = __uint_as_float(v.x << 16);
            acc[1] = __uint_as_float(v.x & 0xffff0000u);
            acc[2] = __uint_as_float(v.y << 16);
            acc[3] = __uint_as_float(v.y & 0xffff0000u);
            acc[4] = __uint_as_float(v.z << 16);
            acc[5] = __uint_as_float(v.z & 0xffff0000u);
            acc[6] = __uint_as_float(v.w << 16);
            acc[7] = __uint_as_float(v.w & 0xffff0000u);
        }
        unsigned o = off[node];
        unsigned d = cnt[node];

        unsigned e = 0;
        for (; e + 4 <= d; e += 4) {
            int s0 = csr[o + e + 0];
            int s1 = csr[o + e + 1];
            int s2 = csr[o + e + 2];
            int s3 = csr[o + e + 3];
            uint4 v0 = Abf[(size_t)s0 * 16 + lane];
            uint4 v1 = Abf[(size_t)s1 * 16 + lane];
            uint4 v2 = Abf[(size_t)s2 * 16 + lane];
            uint4 v3 = Abf[(size_t)s3 * 16 + lane];
            bf8_add(acc, v0);
            bf8_add(acc, v1);
            bf8_add(acc, v2);
            bf8_add(acc, v3);
        }
        for (; e < d; ++e) {
            int s = csr[o + e];
            uint4 v = Abf[(size_t)s * 16 + lane];
            bf8_add(acc, v);
        }

        float nm = nrm[node];
        float4 b0 = *(const float4*)(bias + lane * 8);
        float4 b1 = *(const float4*)(bias + lane * 8 + 4);
        unsigned short* p = &sA[g][lane * 8];
        p[0] = f2bf(fmaxf(acc[0] * nm + b0.x, 0.f));
        p[1] = f2bf(fmaxf(acc[1] * nm + b0.y, 0.f));
        p[2] = f2bf(fmaxf(acc[2] * nm + b0.z, 0.f));
        p[3] = f2bf(fmaxf(acc[3] * nm + b0.w, 0.f));
        p[4] = f2bf(fmaxf(acc[4] * nm + b1.x, 0.f));
        p[5] = f2bf(fmaxf(acc[5] * nm + b1.y, 0.f));
        p[6] = f2bf(fmaxf(acc[6] * nm + b1.z, 0.f));
        p[7] = f2bf(fmaxf(acc[7] * nm + b1.w, 0.f));
    }
    __syncthreads();
}

// ---------------- fused: aggregate + next-layer GEMM ------------------------
// Block = 16 nodes. Phase 1: gather -> z bf16 in LDS. Phase 2: 16x128 MFMA
// tile vs Wt; out = bf16(nrm[r] * (z @ W)). Bit-identical to agg->Bb->gemm.

__global__ __launch_bounds__(256) void agg_gemm(const uint4* __restrict__ Abf,
                                                const int* __restrict__ csr,
                                                const unsigned* __restrict__ off,
                                                const unsigned* __restrict__ cnt,
                                                const float* __restrict__ nrm,
                                                const float* __restrict__ bias,
                                                const unsigned short* __restrict__ Wt,
                                                unsigned short* __restrict__ outb, int N) {
    __shared__ unsigned short sA[16][SP];
    gather_phase(Abf, csr, off, cnt, nrm, bias, sA, N);

    const int tid = threadIdx.x;
    const int wave = tid >> 6;
    const int l64 = tid & 63;
    const int m = l64 & 15;
    const int quad = l64 >> 4;

    f32x4 acc[2];
    acc[0] = (f32x4){0.f, 0.f, 0.f, 0.f};
    acc[1] = (f32x4){0.f, 0.f, 0.f, 0.f};

#pragma unroll
    for (int kt = 0; kt < 4; ++kt) {
        const int kof = kt * 32 + quad * 8;
        bf16x8 a = *(const bf16x8*)&sA[m][kof];
#pragma unroll
        for (int c2 = 0; c2 < 2; ++c2) {
            const int ct = wave * 2 + c2;
            bf16x8 b = *(const bf16x8*)(Wt + (ct * 16 + m) * DH + kof);
            acc[c2] = __builtin_amdgcn_mfma_f32_16x16x32_bf16(a, b, acc[c2], 0, 0, 0);
        }
    }

#pragma unroll
    for (int reg = 0; reg < 4; ++reg) {
        int r = blockIdx.x * 16 + quad * 4 + reg;
        if (r < N) {
            float s = nrm[r];
#pragma unroll
            for (int c2 = 0; c2 < 2; ++c2)
                outb[(size_t)r * DH + (wave * 2 + c2) * 16 + m] = f2bf(acc[c2][reg] * s);
        }
    }
}

// ---------------- fused: aggregate + head GEMM + log_softmax ----------------

__global__ __launch_bounds__(256) void agg_head(const uint4* __restrict__ Abf,
                                                const int* __restrict__ csr,
                                                const unsigned* __restrict__ off,
                                                const unsigned* __restrict__ cnt,
                                                const float* __restrict__ nrm,
                                                const float* __restrict__ bias,
                                                const unsigned short* __restrict__ Wft,
                                                const float* __restrict__ bfh,
                                                float* __restrict__ out, int N) {
    __shared__ unsigned short sA[16][SP];
    gather_phase(Abf, csr, off, cnt, nrm, bias, sA, N);

    const int tid = threadIdx.x;
    if (tid >= 64) return;                 // one wave does the 16x48 head
    const int m = tid & 15;
    const int quad = tid >> 4;

    f32x4 acc[3];
#pragma unroll
    for (int ct = 0; ct < 3; ++ct) acc[ct] = (f32x4){0.f, 0.f, 0.f, 0.f};

#pragma unroll
    for (int kt = 0; kt < 4; ++kt) {
        const int kof = kt * 32 + quad * 8;
        bf16x8 a = *(const bf16x8*)&sA[m][kof];
#pragma unroll
        for (int ct = 0; ct < 3; ++ct) {
            bf16x8 b = *(const bf16x8*)(Wft + (ct * 16 + m) * DH + kof);
            acc[ct] = __builtin_amdgcn_mfma_f32_16x16x32_bf16(a, b, acc[ct], 0, 0, 0);
        }
    }

    float bias0 = bfh[m];
    float bias1 = bfh[16 + m];
    float bias2 = bfh[32 + m];

#pragma unroll
    for (int reg = 0; reg < 4; ++reg) {
        float v0 = acc[0][reg] + bias0;
        float v1 = acc[1][reg] + bias1;
        float v2 = (m < 8) ? (acc[2][reg] + bias2) : -1e30f;
        float mx = fmaxf(fmaxf(v0, v1), v2);
#pragma unroll
        for (int dlt = 1; dlt < 16; dlt <<= 1) mx = fmaxf(mx, __shfl_xor(mx, dlt));
        float s = __expf(v0 - mx) + __expf(v1 - mx) + ((m < 8) ? __expf(v2 - mx) : 0.f);
#pragma unroll
        for (int dlt = 1; dlt < 16; dlt <<= 1) s += __shfl_xor(s, dlt);
        float ls = mx + __logf(s);
        int r = blockIdx.x * 16 + quad * 4 + reg;
        if (r < N) {
            out[(size_t)r * NC + m] = v0 - ls;
            out[(size_t)r * NC + 16 + m] = v1 - ls;
            if (m < 8) out[(size_t)r * NC + 32 + m] = v2 - ls;
        }
    }
}

// ---------------------------------------------------------------------------

extern "C" void kernel_launch(void* const* d_in, const int* in_sizes, int n_in,
                              void* d_out, int out_size, void* d_ws, size_t ws_size,
                              hipStream_t stream) {
    const float* x   = (const float*)d_in[0];
    const int*   ei  = (const int*)d_in[1];
    const float* W1  = (const float*)d_in[2];
    const float* b1  = (const float*)d_in[3];
    const float* W2  = (const float*)d_in[4];
    const float* b2  = (const float*)d_in[5];
    const float* W3  = (const float*)d_in[6];
    const float* b3  = (const float*)d_in[7];
    const float* Wp1 = (const float*)d_in[8];
    const float* bp1 = (const float*)d_in[9];
    const float* Wp2 = (const float*)d_in[10];
    const float* bp2 = (const float*)d_in[11];
    float* out = (float*)d_out;

    const int N = in_sizes[0] / DH;
    const int E = in_sizes[1] / 2;
    const int* src = ei;
    const int* dst = ei + E;
    const int NB = (N + BN - 1) / BN;

    // workspace carve (all 16B aligned)
    char* w = (char*)d_ws;
    unsigned short* Ab  = (unsigned short*)w; w += (size_t)N * DH * 2;
    unsigned short* Bb  = (unsigned short*)w; w += (size_t)N * DH * 2;
    int*      csr    = (int*)w;      w += (size_t)E * 4;
    unsigned* ebuf   = (unsigned*)w; w += (size_t)E * 4;
    unsigned* bcnt   = (unsigned*)w; w += MAXNB * 4;
    unsigned* cursor = (unsigned*)w; w += 16;
    unsigned* bbase  = (unsigned*)w; w += MAXNB * 4;
    unsigned* bpos   = (unsigned*)w; w += MAXNB * 4;
    unsigned* off    = (unsigned*)w; w += (size_t)N * 4;
    unsigned* cnt    = (unsigned*)w; w += (size_t)N * 4;
    float*    nrm    = (float*)w;    w += (size_t)N * 4;
    unsigned short* Wt  = (unsigned short*)w; w += 3 * DH * DH * 2;
    unsigned short* Wft = (unsigned short*)w; w += 48 * DH * 2;
    float*    bfh    = (float*)w;    w += 64 * 4;

    const int gC = (E + CH - 1) / CH;

    hipMemsetAsync(bcnt, 0, MAXNB * 4 + 16, stream);   // bcnt + cursor
    bucket_hist   <<<gC, 256, 0, stream>>>(dst, E, bcnt);
    bucket_alloc  <<<(NB + 255) / 256, 256, 0, stream>>>(bcnt, bbase, bpos, cursor, NB);
    bucket_scatter<<<gC, 256, 0, stream>>>(src, dst, E, bpos, ebuf);
    bucket_csr    <<<NB, 256, 0, stream>>>(ebuf, bbase, bcnt, off, cnt, nrm, csr, N);
    prep_w<<<(3 * DH * DH + 48 * DH + 48 + 255) / 256, 256, 0, stream>>>(
        W1, W2, W3, Wp1, bp1, Wp2, bp2, Wt, Wft, bfh);

    const int gG = (N + 127) / 128;
    const int gF = (N + 15) / 16;

    gemm_mfma_f32<<<gG, 256, 0, stream>>>(x, Wt, nrm, Ab, N);
    agg_gemm<<<gF, 256, 0, stream>>>((const uint4*)Ab, csr, off, cnt, nrm, b1,
                                     Wt + DH * DH, Bb, N);
    agg_gemm<<<gF, 256, 0, stream>>>((const uint4*)Bb, csr, off, cnt, nrm, b2,
                                     Wt + 2 * DH * DH, Ab, N);
    agg_head<<<gF, 256, 0, stream>>>((const uint4*)Ab, csr, off, cnt, nrm, b3,
                                     Wft, bfh, out, N);
}